// Round 3
// baseline (1511.815 us; speedup 1.0000x reference)
//
#include <hip/hip_runtime.h>

#define NN     100000
#define NB     1563          // ceil(100000 / 64)
#define LN_EPS 1e-5f
#define SLOPE  0.01f

typedef __bf16 bf16x8 __attribute__((ext_vector_type(8)));
typedef float  f32x4  __attribute__((ext_vector_type(4)));
typedef unsigned short u16;
typedef unsigned int   u32;

union Pack8 { uint4 u4; bf16x8 bf; u16 s[8]; };

__device__ __forceinline__ u16 f2bf(float x){
    u32 b = __float_as_uint(x);
    b += 0x7fffu + ((b >> 16) & 1u);
    return (u16)(b >> 16);
}

// Pack w[1024][1024] fp32 (row = output col i, inner = k) into bf16 B-fragment
// order: Wp[k>>5][i][k&31]; B-frag load for (col,ks) is uint4 (ks*1024+col)*4+q.
__global__ __launch_bounds__(1024) void prep_weights(
    const float* __restrict__ wa, const float* __restrict__ wb,
    const float* __restrict__ wc, const float* __restrict__ wd,
    u16* __restrict__ dst)
{
    int m = blockIdx.y;
    const float* src = (m==0)? wa : (m==1)? wb : (m==2)? wc : wd;
    u16* d = dst + (size_t)m * (1024u*1024u);
    int tid = blockIdx.x * blockDim.x + threadIdx.x;   // 0..131071
    int sub = tid & 3;
    int row = (tid >> 2) & 1023;
    int kb  = tid >> 12;                               // 0..31
    const float4* s4 = (const float4*)(src + row*1024 + kb*32 + sub*8);
    float4 a = s4[0], b = s4[1];
    Pack8 p;
    p.s[0]=f2bf(a.x); p.s[1]=f2bf(a.y); p.s[2]=f2bf(a.z); p.s[3]=f2bf(a.w);
    p.s[4]=f2bf(b.x); p.s[5]=f2bf(b.y); p.s[6]=f2bf(b.z); p.s[7]=f2bf(b.w);
    ((uint4*)d)[(kb*1024 + row)*4 + sub] = p.u4;
}

// One wave computes 4 column-tiles (cols wv*32..+31, (wv+16)*32..+31) for all
// 64 nodes. A-frags (LDS, K-packed) reused across 4 B-frags; B loads (L2)
// double-buffered in registers so they overlap the 16 MFMAs of the prev step.
__device__ __forceinline__ void gemm_quad(
    const u16* __restrict__ Wp, const u16* xs,
    int wv, int lane15, int q, f32x4 acc[4][4])
{
    const uint4* bA = (const uint4*)Wp + (wv*32 + lane15)*4 + q;
    const uint4* bB = (const uint4*)Wp + ((wv+16)*32 + lane15)*4 + q;
    const uint4* ab = (const uint4*)xs + q*64 + lane15;
    #pragma unroll
    for (int ct=0; ct<4; ++ct)
      #pragma unroll
      for (int rt=0; rt<4; ++rt)
        acc[ct][rt] = (f32x4){0.f,0.f,0.f,0.f};
    uint4 nb0 = bA[0], nb1 = bA[64], nb2 = bB[0], nb3 = bB[64];
    #pragma unroll 4
    for (int ks=0; ks<32; ++ks){
        Pack8 b0, b1, b2, b3, a0, a1, a2, a3;
        b0.u4 = nb0; b1.u4 = nb1; b2.u4 = nb2; b3.u4 = nb3;
        const int kn = (ks+1) & 31;      // ks=31 redundantly reloads 0 (no branch)
        nb0 = bA[kn*4096];
        nb1 = bA[kn*4096 + 64];
        nb2 = bB[kn*4096];
        nb3 = bB[kn*4096 + 64];
        a0.u4 = ab[ks*256];
        a1.u4 = ab[ks*256 + 16];
        a2.u4 = ab[ks*256 + 32];
        a3.u4 = ab[ks*256 + 48];
        acc[0][0] = __builtin_amdgcn_mfma_f32_16x16x32_bf16(a0.bf, b0.bf, acc[0][0], 0,0,0);
        acc[0][1] = __builtin_amdgcn_mfma_f32_16x16x32_bf16(a1.bf, b0.bf, acc[0][1], 0,0,0);
        acc[0][2] = __builtin_amdgcn_mfma_f32_16x16x32_bf16(a2.bf, b0.bf, acc[0][2], 0,0,0);
        acc[0][3] = __builtin_amdgcn_mfma_f32_16x16x32_bf16(a3.bf, b0.bf, acc[0][3], 0,0,0);
        acc[1][0] = __builtin_amdgcn_mfma_f32_16x16x32_bf16(a0.bf, b1.bf, acc[1][0], 0,0,0);
        acc[1][1] = __builtin_amdgcn_mfma_f32_16x16x32_bf16(a1.bf, b1.bf, acc[1][1], 0,0,0);
        acc[1][2] = __builtin_amdgcn_mfma_f32_16x16x32_bf16(a2.bf, b1.bf, acc[1][2], 0,0,0);
        acc[1][3] = __builtin_amdgcn_mfma_f32_16x16x32_bf16(a3.bf, b1.bf, acc[1][3], 0,0,0);
        acc[2][0] = __builtin_amdgcn_mfma_f32_16x16x32_bf16(a0.bf, b2.bf, acc[2][0], 0,0,0);
        acc[2][1] = __builtin_amdgcn_mfma_f32_16x16x32_bf16(a1.bf, b2.bf, acc[2][1], 0,0,0);
        acc[2][2] = __builtin_amdgcn_mfma_f32_16x16x32_bf16(a2.bf, b2.bf, acc[2][2], 0,0,0);
        acc[2][3] = __builtin_amdgcn_mfma_f32_16x16x32_bf16(a3.bf, b2.bf, acc[2][3], 0,0,0);
        acc[3][0] = __builtin_amdgcn_mfma_f32_16x16x32_bf16(a0.bf, b3.bf, acc[3][0], 0,0,0);
        acc[3][1] = __builtin_amdgcn_mfma_f32_16x16x32_bf16(a1.bf, b3.bf, acc[3][1], 0,0,0);
        acc[3][2] = __builtin_amdgcn_mfma_f32_16x16x32_bf16(a2.bf, b3.bf, acc[3][2], 0,0,0);
        acc[3][3] = __builtin_amdgcn_mfma_f32_16x16x32_bf16(a3.bf, b3.bf, acc[3][3], 0,0,0);
    }
}

// LDS layout (floats):
//   [0, 32832)       : xs (bf16 activations, 131072 B) / later sbuf (fp32 h2)
//   [32832, +64*VSTR): vbuf, per-node padded v rows
//   then 128 floats  : stats (64 nodes x {sum, sumsq})
template<int MDIM>
__global__ __launch_bounds__(1024, 4) void gal_fused(
    const float* __restrict__ f,
    const float* __restrict__ ln1g, const float* __restrict__ ln1b,
    const float* __restrict__ ln2g, const float* __restrict__ ln2b,
    const float* __restrict__ b2,
    const u16* __restrict__ Wp1, const u16* __restrict__ Wp2,
    float* __restrict__ outp)
{
    extern __shared__ char smem[];
    constexpr int VSTR = 32*MDIM + 4;           // padded node stride (floats)
    constexpr int SBS  = 64*32 + 4;             // sbuf per-wave stride = 2052
    u16*   xs    = (u16*)smem;
    float* sbuf  = (float*)smem;
    float* vbuf  = (float*)smem + 32832;
    float* stats = (float*)smem + 32832 + 64*VSTR;

    const int tid    = threadIdx.x;
    const int lane   = tid & 63;
    const int wv     = tid >> 6;
    const int lane15 = lane & 15;
    const int q      = lane >> 4;
    const int node0  = blockIdx.x * 64;

    // ---- Phase 0: zero stats, stage v tile (float4, padded, zero-fill)
    if (tid < 128) stats[tid] = 0.f;
    {
        float4* vbuf4 = (float4*)vbuf;
        const int gv4  = node0*8*MDIM;          // block base in float4 units
        const int lim4 = NN*8*MDIM;
        for (int i = tid; i < 64*8*MDIM; i += 1024){
            int nd = i / (8*MDIM);
            int r4 = i - nd*(8*MDIM);
            float4 val = (gv4 + i < lim4) ? ((const float4*)f)[gv4 + i]
                                          : (float4){0.f,0.f,0.f,0.f};
            vbuf4[nd*(VSTR/4) + r4] = val;
        }
    }
    __syncthreads();

    // ---- Phase 1: gram + LN1 + lrelu -> xs (bf16, [k>>3][node][k&7])
    {
        const int n = tid >> 4;          // node
        const int j = tid & 15;          // owns k = j*64 .. j*64+63
        const float* vn = vbuf + n*VSTR;
        float va[2][MDIM];
        #pragma unroll
        for (int c=0;c<MDIM;++c){ va[0][c]=vn[(j*2)*MDIM+c]; va[1][c]=vn[(j*2+1)*MDIM+c]; }
        float sum=0.f, ssum=0.f;
        #pragma unroll
        for (int b=0;b<32;++b){
            float d0=0.f, d1=0.f;
            #pragma unroll
            for (int c=0;c<MDIM;++c){ float vb = vn[b*MDIM+c]; d0 += va[0][c]*vb; d1 += va[1][c]*vb; }
            sum += d0+d1; ssum += d0*d0 + d1*d1;
        }
        #pragma unroll
        for (int st=1; st<16; st<<=1){ sum += __shfl_xor(sum, st); ssum += __shfl_xor(ssum, st); }
        float mu   = sum * (1.f/1024.f);
        float rstd = rsqrtf(ssum*(1.f/1024.f) - mu*mu + LN_EPS);
        #pragma unroll
        for (int jb=0;jb<8;++jb){
            const int k0 = j*64 + jb*8;
            float4 ga = ((const float4*)(ln1g + k0))[0];
            float4 gb = ((const float4*)(ln1g + k0))[1];
            float4 ba = ((const float4*)(ln1b + k0))[0];
            float4 bb = ((const float4*)(ln1b + k0))[1];
            float gg[8] = {ga.x,ga.y,ga.z,ga.w,gb.x,gb.y,gb.z,gb.w};
            float bbv[8] = {ba.x,ba.y,ba.z,ba.w,bb.x,bb.y,bb.z,bb.w};
            Pack8 p;
            const int ai = jb >> 2;
            #pragma unroll
            for (int l=0;l<8;++l){
                int b = (jb*8+l) & 31;
                float d = 0.f;
                #pragma unroll
                for (int c=0;c<MDIM;++c) d += va[ai][c]*vn[b*MDIM+c];
                float x = (d - mu)*rstd*gg[l] + bbv[l];
                x = (x >= 0.f)? x : SLOPE*x;
                p.s[l] = f2bf(x);
            }
            ((uint4*)xs)[(j*8+jb)*64 + n] = p.u4;
        }
    }
    __syncthreads();

    // ---- Phase 2: h1 = x1 @ W1^T. Stats via multi-value fold-tree + one
    // atomic pair. acc stays live in AGPRs across the barrier (no stash).
    {
        f32x4 acc[4][4];
        gemm_quad(Wp1, xs, wv, lane15, q, acc);
        {
            float p_[16], pp_[16];
            #pragma unroll
            for (int idx=0; idx<16; ++idx){
                int rt = idx>>2, rr = idx&3;
                float s=0.f, s2=0.f;
                #pragma unroll
                for (int ct=0; ct<4; ++ct){
                    float h = acc[ct][rt][rr];
                    s += h; s2 += h*h;
                }
                p_[idx] = s; pp_[idx] = s2;
            }
            // fold-tree: lane15==l ends with totals for idx l in slot [0]
            #pragma unroll
            for (int m=8; m>=1; m>>=1){
                const bool hi = (lane15 & m) != 0;
                #pragma unroll
                for (int i=0; i<m; ++i){
                    float sp = hi ? p_[i]  : p_[i+m];
                    float kp = hi ? p_[i+m]  : p_[i];
                    p_[i]  = kp + __shfl_xor(sp, m);
                    float sq = hi ? pp_[i] : pp_[i+m];
                    float kq = hi ? pp_[i+m] : pp_[i];
                    pp_[i] = kq + __shfl_xor(sq, m);
                }
            }
            int nd = (lane15>>2)*16 + q*4 + (lane15&3);
            atomicAdd(&stats[2*nd],   p_[0]);
            atomicAdd(&stats[2*nd+1], pp_[0]);
        }
        __syncthreads();   // stats final AND all GEMM1 xs reads drained

        // ---- Phase 3: LN2 + lrelu applied to acc in regs -> x2 into xs
        float g2c[4], b2c[4];
        #pragma unroll
        for (int ct=0; ct<4; ++ct){
            int col = (wv + (ct>>1)*16)*32 + (ct&1)*16 + lane15;
            g2c[ct] = ln2g[col];
            b2c[ct] = ln2b[col];
        }
        #pragma unroll
        for (int rt=0; rt<4; ++rt)
          #pragma unroll
          for (int rr=0; rr<4; ++rr){
            int nd = rt*16 + q*4 + rr;
            float mu   = stats[2*nd]*(1.f/1024.f);
            float rstd = rsqrtf(stats[2*nd+1]*(1.f/1024.f) - mu*mu + LN_EPS);
            #pragma unroll
            for (int ct=0; ct<4; ++ct){
                float h = acc[ct][rt][rr];
                float x = (h - mu)*rstd*g2c[ct] + b2c[ct];
                x = (x >= 0.f)? x : SLOPE*x;
                int col = (wv + (ct>>1)*16)*32 + (ct&1)*16 + lane15;
                xs[(col>>3)*512 + nd*8 + (col&7)] = f2bf(x);
            }
          }
    }
    __syncthreads();

    // ---- Phase 4: h2 = x2 @ W2^T + b2; stage each a-strip (fp32) into the
    // retired xs region; then one thread per (node, a): softmax + attn @ v.
    {
        f32x4 acc[4][4];
        gemm_quad(Wp2, xs, wv, lane15, q, acc);
        float bias[4];
        #pragma unroll
        for (int ct=0; ct<4; ++ct)
            bias[ct] = b2[(wv + (ct>>1)*16)*32 + (ct&1)*16 + lane15];
        __syncthreads();   // all xs reads complete before sbuf overwrite

        #pragma unroll
        for (int si=0; si<2; ++si){
            // stage strip a = wv + si*16 : sbuf[wv][node][b]
            #pragma unroll
            for (int ctl=0; ctl<2; ++ctl){
                const int ct = si*2 + ctl;
                #pragma unroll
                for (int rt=0; rt<4; ++rt)
                  #pragma unroll
                  for (int rr=0; rr<4; ++rr){
                    int nd = rt*16 + q*4 + rr;
                    sbuf[wv*SBS + nd*32 + ctl*16 + lane15] = acc[ct][rt][rr] + bias[ct];
                  }
            }
            __syncthreads();
            // consume: thread -> (node = tid>>4, a = (tid&15) + si*16)
            {
                const int nd  = tid >> 4;
                const int a15 = tid & 15;
                const float* hp = sbuf + a15*SBS + nd*32;
                float e[32];
                #pragma unroll
                for (int r=0;r<8;++r){
                    float4 v4 = ((const float4*)hp)[r];
                    e[4*r]=v4.x; e[4*r+1]=v4.y; e[4*r+2]=v4.z; e[4*r+3]=v4.w;
                }
                float mx = e[0];
                #pragma unroll
                for (int b=1;b<32;++b) mx = fmaxf(mx, e[b]);
                float sm = 0.f;
                #pragma unroll
                for (int b=0;b<32;++b){ e[b] = __expf(e[b]-mx); sm += e[b]; }
                float inv = 1.f / sm;
                float oacc[MDIM];
                #pragma unroll
                for (int c=0;c<MDIM;++c) oacc[c]=0.f;
                const float4* vr = (const float4*)(vbuf + nd*VSTR);
                #pragma unroll
                for (int r=0; r<8*MDIM; ++r){
                    float4 v4 = vr[r];
                    #pragma unroll
                    for (int t=0;t<4;++t){
                        const int fi = 4*r+t;
                        const int b  = fi/MDIM;
                        const int c  = fi - b*MDIM;
                        float comp = (t==0)?v4.x:(t==1)?v4.y:(t==2)?v4.z:v4.w;
                        oacc[c] += e[b]*comp;
                    }
                }
                int ng = node0 + nd;
                if (ng < NN){
                    #pragma unroll
                    for (int c=0;c<MDIM;++c)
                        outp[((size_t)ng*32 + a15 + si*16)*MDIM + c] = oacc[c]*inv;
                }
            }
            if (si==0) __syncthreads();   // WAR on sbuf before next stage
        }
    }
}

extern "C" void kernel_launch(void* const* d_in, const int* in_sizes, int n_in,
                              void* d_out, int out_size, void* d_ws, size_t ws_size,
                              hipStream_t stream)
{
    const float* f0    = (const float*)d_in[0];
    const float* f1    = (const float*)d_in[1];
    const float* ln1g0 = (const float*)d_in[2];
    const float* ln1b0 = (const float*)d_in[3];
    const float* w1_0  = (const float*)d_in[4];
    const float* ln2g0 = (const float*)d_in[5];
    const float* ln2b0 = (const float*)d_in[6];
    const float* w2_0  = (const float*)d_in[7];
    const float* b2_0  = (const float*)d_in[8];
    const float* ln1g1 = (const float*)d_in[9];
    const float* ln1b1 = (const float*)d_in[10];
    const float* w1_1  = (const float*)d_in[11];
    const float* ln2g1 = (const float*)d_in[12];
    const float* ln2b1 = (const float*)d_in[13];
    const float* w2_1  = (const float*)d_in[14];
    const float* b2_1  = (const float*)d_in[15];
    float* out = (float*)d_out;
    u16* wp = (u16*)d_ws;    // 4 packed matrices x 2 MB = 8 MB scratch

    const int smem1 = (32832 + 64*(32*1+4) + 128)*4;   // 141056
    const int smem3 = (32832 + 64*(32*3+4) + 128)*4;   // 157440
    (void)hipFuncSetAttribute(reinterpret_cast<const void*>(&gal_fused<1>),
                              hipFuncAttributeMaxDynamicSharedMemorySize, smem1);
    (void)hipFuncSetAttribute(reinterpret_cast<const void*>(&gal_fused<3>),
                              hipFuncAttributeMaxDynamicSharedMemorySize, smem3);

    prep_weights<<<dim3(128,4), 1024, 0, stream>>>(w1_0, w2_0, w1_1, w2_1, wp);
    gal_fused<1><<<NB, 1024, smem1, stream>>>(f0, ln1g0, ln1b0, ln2g0, ln2b0, b2_0,
                                              wp,            wp + 1048576, out);
    gal_fused<3><<<NB, 1024, smem3, stream>>>(f1, ln1g1, ln1b1, ln2g1, ln2b1, b2_1,
                                              wp + 2097152,  wp + 3145728, out + (size_t)NN*32);
}